// Round 5
// baseline (64.200 us; speedup 1.0000x reference)
//
#include <hip/hip_runtime.h>

#define NDIM 1024
#define BDIM 128
#define TS 32
#define NT (NDIM / TS)                 // 32
#define NTILES (NT * (NT + 1) / 2)     // 528 upper-tri tiles

// One block per upper-tri 32x32 tile. Per tile row i (masked to triu):
//   contribution(b) = q_bi * RS_i + r_bi * (sum_j W_ij * v_bj)
// q=1-v, r=2v-1, RS_i = masked row sum. 1 MAC per W element.
// Lane l owns the ADJACENT batch pair b=(2l,2l+1) so all per-b LDS traffic
// is float2 (ds_*_b64): halves LDS instruction count vs scalar b32.
// Wave w owns tile rows [8w, 8w+8).
__global__ __launch_bounds__(256) void potts_main(
    const float* __restrict__ V,      // [128][1024]
    const float* __restrict__ W,      // [1024][1024]
    float* __restrict__ partial)      // [NTILES][128]
{
    const int t = blockIdx.x;
    int ti = 0, rem = t;
    while (rem >= NT - ti) { rem -= NT - ti; ++ti; }
    const int tj = ti + rem;
    const int I0 = ti * TS, J0 = tj * TS;
    const bool diag = (ti == tj);

    __shared__ float wt[TS][36];        // broadcast rows, 16B-aligned
    __shared__ float rs[TS];            // masked row sums
    __shared__ float vjt[TS][130];      // V[:,J0+j] transposed [j][b]
    __shared__ float vit[TS][130];      // V[:,I0+i] transposed [i][b]
    __shared__ float red[4][BDIM];

    const int tid = threadIdx.x;
    const int w = tid >> 6;
    const int l = tid & 63;

    // ---- stage masked W tile (coalesced float4) + row sums via shfl
    {
        const int r = tid >> 3, c4 = (tid & 7) * 4;
        float4 w4 = *(const float4*)(W + (size_t)(I0 + r) * NDIM + (J0 + c4));
        if (diag) {                      // triu: keep j >= i
            if (c4 + 0 < r) w4.x = 0.0f;
            if (c4 + 1 < r) w4.y = 0.0f;
            if (c4 + 2 < r) w4.z = 0.0f;
            if (c4 + 3 < r) w4.w = 0.0f;
        }
        *(float4*)(&wt[r][c4]) = w4;
        float rsum = (w4.x + w4.y) + (w4.z + w4.w);
        rsum += __shfl_xor(rsum, 1);
        rsum += __shfl_xor(rsum, 2);
        rsum += __shfl_xor(rsum, 4);
        if ((tid & 7) == 0) rs[r] = rsum;
    }

    // ---- stage V slices transposed with float2 LDS writes.
    // Task = (row-pair p, float4-group g): read V[2p][4g..4g+3], V[2p+1][...],
    // write 4 x float2 {a,c} into vjt/vit[4g+m][2p]. 512 tasks per slice.
    for (int it = 0; it < 2; ++it) {
        const int task = tid + 256 * it;
        const int p = task >> 3, g = task & 7;
        {
            const float4 a = *(const float4*)(V + (size_t)(2 * p) * NDIM + J0 + 4 * g);
            const float4 c = *(const float4*)(V + (size_t)(2 * p + 1) * NDIM + J0 + 4 * g);
            *(float2*)(&vjt[4 * g + 0][2 * p]) = make_float2(a.x, c.x);
            *(float2*)(&vjt[4 * g + 1][2 * p]) = make_float2(a.y, c.y);
            *(float2*)(&vjt[4 * g + 2][2 * p]) = make_float2(a.z, c.z);
            *(float2*)(&vjt[4 * g + 3][2 * p]) = make_float2(a.w, c.w);
        }
        {
            const float4 a = *(const float4*)(V + (size_t)(2 * p) * NDIM + I0 + 4 * g);
            const float4 c = *(const float4*)(V + (size_t)(2 * p + 1) * NDIM + I0 + 4 * g);
            *(float2*)(&vit[4 * g + 0][2 * p]) = make_float2(a.x, c.x);
            *(float2*)(&vit[4 * g + 1][2 * p]) = make_float2(a.y, c.y);
            *(float2*)(&vit[4 * g + 2][2 * p]) = make_float2(a.z, c.z);
            *(float2*)(&vit[4 * g + 3][2 * p]) = make_float2(a.w, c.w);
        }
    }
    __syncthreads();

    // ---- per-lane vj registers: 32 x ds_read_b64 (b pair adjacent)
    float vj0[TS], vj1[TS];
#pragma unroll
    for (int j = 0; j < TS; ++j) {
        const float2 p2 = *(const float2*)(&vjt[j][2 * l]);
        vj0[j] = p2.x;
        vj1[j] = p2.y;
    }

    float acc0 = 0.0f, acc1 = 0.0f;
#pragma unroll
    for (int k = 0; k < 8; ++k) {
        const int i = 8 * w + k;
        const float2 vi2 = *(const float2*)(&vit[i][2 * l]);   // 1 b64
        const float q0 = 1.0f - vi2.x, r0 = 2.0f * vi2.x - 1.0f;
        const float q1 = 1.0f - vi2.y, r1 = 2.0f * vi2.y - 1.0f;
        const float* wrow = &wt[i][0];
        float za0 = 0.f, zb0 = 0.f, za1 = 0.f, zb1 = 0.f;      // 4 indep chains
#pragma unroll
        for (int j4 = 0; j4 < 8; j4 += 2) {
            const float4 wa = *(const float4*)(wrow + 4 * j4);     // broadcast b128
            const float4 wb = *(const float4*)(wrow + 4 * j4 + 4); // broadcast b128
            za0 = fmaf(wa.x, vj0[4 * j4 + 0], za0);
            za0 = fmaf(wa.y, vj0[4 * j4 + 1], za0);
            za0 = fmaf(wa.z, vj0[4 * j4 + 2], za0);
            za0 = fmaf(wa.w, vj0[4 * j4 + 3], za0);
            za1 = fmaf(wa.x, vj1[4 * j4 + 0], za1);
            za1 = fmaf(wa.y, vj1[4 * j4 + 1], za1);
            za1 = fmaf(wa.z, vj1[4 * j4 + 2], za1);
            za1 = fmaf(wa.w, vj1[4 * j4 + 3], za1);
            zb0 = fmaf(wb.x, vj0[4 * j4 + 4], zb0);
            zb0 = fmaf(wb.y, vj0[4 * j4 + 5], zb0);
            zb0 = fmaf(wb.z, vj0[4 * j4 + 6], zb0);
            zb0 = fmaf(wb.w, vj0[4 * j4 + 7], zb0);
            zb1 = fmaf(wb.x, vj1[4 * j4 + 4], zb1);
            zb1 = fmaf(wb.y, vj1[4 * j4 + 5], zb1);
            zb1 = fmaf(wb.z, vj1[4 * j4 + 6], zb1);
            zb1 = fmaf(wb.w, vj1[4 * j4 + 7], zb1);
        }
        const float rsk = rs[i];                                // broadcast
        acc0 = fmaf(q0, rsk, acc0);
        acc0 = fmaf(r0, za0 + zb0, acc0);
        acc1 = fmaf(q1, rsk, acc1);
        acc1 = fmaf(r1, za1 + zb1, acc1);
    }

    *(float2*)(&red[w][2 * l]) = make_float2(acc0, acc1);       // 1 b64
    __syncthreads();
    if (tid < BDIM) {
        partial[t * BDIM + tid] =
            (red[0][tid] + red[1][tid]) + (red[2][tid] + red[3][tid]);
    }
}

// ---- reduce 528 tile partials -> out[b]; one block per b
__global__ __launch_bounds__(64) void potts_red(
    const float* __restrict__ partial, float* __restrict__ out)
{
    const int b = blockIdx.x;
    const int lane = threadIdx.x;
    float a0 = 0.f, a1 = 0.f;
    int t = lane;
#pragma unroll 4
    for (; t + 64 < NTILES; t += 128) {
        a0 += partial[t * BDIM + b];
        a1 += partial[(t + 64) * BDIM + b];
    }
    if (t < NTILES) a0 += partial[t * BDIM + b];
    float a = a0 + a1;
#pragma unroll
    for (int off = 32; off > 0; off >>= 1)
        a += __shfl_down(a, off);
    if (lane == 0) out[b] = a;
}

extern "C" void kernel_launch(void* const* d_in, const int* in_sizes, int n_in,
                              void* d_out, int out_size, void* d_ws, size_t ws_size,
                              hipStream_t stream) {
    const float* V = (const float*)d_in[0];
    const float* W = (const float*)d_in[1];
    float* out = (float*)d_out;
    float* partial = (float*)d_ws;            // 528*128*4 = 270336 B

    potts_main<<<dim3(NTILES), dim3(256), 0, stream>>>(V, W, partial);
    potts_red<<<dim3(BDIM), dim3(64), 0, stream>>>(partial, out);
}